// Round 2
// baseline (847.026 us; speedup 1.0000x reference)
//
#include <hip/hip_runtime.h>
#include <math.h>

// ---------------------------------------------------------------------------
// GCN dual-branch, algebraically restructured:
//   ax = A'x  (128 feats)            [A' = D^-1/2 (A+I) D^-1/2]
//   branch1: y16 = relu(ax@W1 + b1) @ (W2@Wc); cls = A'(y16) + (b2@Wc+bc)
//   branch2 (fully linear): g1 = ax@Me + c1 ; g_{k+1} = A'(g_k) + c_{k+1}
//            trust = sigmoid(A'(g3) + be4@Wt + bt)
//   Me = We1@We2@We3@We4@Wt (128x2); c_k = be_k @ (tail-chain)
// edge_index is INT32 (JAX x64 disabled demotes int64 -> int32).
// ---------------------------------------------------------------------------

// small-area offsets (floats) inside workspace
#define SM_W2C   0        // 256*16
#define SM_T4    4096     // 128*2
#define SM_T3    4352
#define SM_T2    4608
#define SM_ME    4864
#define SM_CLSC  5120     // 16
#define SM_C1    5136     // 2
#define SM_C2    5138
#define SM_C3    5140
#define SM_FC    5142     // 2  (be4@Wt + bt)
#define SM_TOTAL 5248

__global__ __launch_bounds__(256) void k_deg(const int* __restrict__ ei,
                                             int* __restrict__ deg, int E, int N) {
  int e = blockIdx.x * 256 + threadIdx.x;
  if (e < E) {
    unsigned c = (unsigned)ei[E + e];
    if (c >= (unsigned)N) c = 0;  // defensive: wrong dtype shows as absmax, not fault
    atomicAdd(&deg[c], 1);
  }
}

__global__ __launch_bounds__(256) void k_dis(const int* __restrict__ deg,
                                             float* __restrict__ dis, int N) {
  int i = blockIdx.x * 256 + threadIdx.x;
  if (i < N) dis[i] = 1.0f / sqrtf((float)deg[i] + 1.0f);
}

// single-block exclusive scan: rowptr[0]=0, rowptr[i+1]=sum cnt[0..i]
__global__ __launch_bounds__(1024) void k_scan(const int* __restrict__ cnt,
                                               int* __restrict__ rowptr, int n) {
  __shared__ int wsum[16];
  __shared__ int s_carry;
  int tid = threadIdx.x, lane = tid & 63, wid = tid >> 6;
  if (tid == 0) { s_carry = 0; rowptr[0] = 0; }
  __syncthreads();
  for (int base = 0; base < n; base += 1024) {
    int i = base + tid;
    int v = (i < n) ? cnt[i] : 0;
    int x = v;
    #pragma unroll
    for (int off = 1; off < 64; off <<= 1) {
      int t = __shfl_up(x, off, 64);
      if (lane >= off) x += t;
    }
    if (lane == 63) wsum[wid] = x;
    __syncthreads();
    if (wid == 0 && lane < 16) {
      int ws = wsum[lane];
      #pragma unroll
      for (int off = 1; off < 16; off <<= 1) {
        int t = __shfl_up(ws, off, 64);
        if (lane >= off) ws += t;
      }
      wsum[lane] = ws;
    }
    __syncthreads();
    int incl = x + (wid ? wsum[wid - 1] : 0);
    int carry = s_carry;
    if (i < n) rowptr[i + 1] = carry + incl;
    __syncthreads();
    if (tid == 1023) s_carry = carry + incl;
    __syncthreads();
  }
}

__global__ __launch_bounds__(256) void k_scatter(const int* __restrict__ ei,
                                                 const int* __restrict__ rowptr,
                                                 int* __restrict__ cnt,
                                                 const float* __restrict__ dis,
                                                 int* __restrict__ csr_src,
                                                 float* __restrict__ csr_w,
                                                 int E, int N) {
  int e = blockIdx.x * 256 + threadIdx.x;
  if (e >= E) return;
  unsigned r = (unsigned)ei[e];
  unsigned c = (unsigned)ei[E + e];
  if (r >= (unsigned)N) r = 0;
  if (c >= (unsigned)N) c = 0;
  int pos = rowptr[c] + atomicAdd(&cnt[c], 1);
  csr_src[pos] = (int)r;
  csr_w[pos] = dis[r] * dis[c];
}

// fold all weight chains (runs once per call, 1 block)
__global__ __launch_bounds__(256) void k_precompute(
    const float* __restrict__ W2, const float* __restrict__ b2,
    const float* __restrict__ Wc, const float* __restrict__ bc,
    const float* __restrict__ We1, const float* __restrict__ be1,
    const float* __restrict__ We2, const float* __restrict__ be2,
    const float* __restrict__ We3, const float* __restrict__ be3,
    const float* __restrict__ We4, const float* __restrict__ be4,
    const float* __restrict__ Wt, const float* __restrict__ bt,
    float* __restrict__ sm) {
  int tid = threadIdx.x;
  {
    int r = tid >> 1, c = tid & 1; float s = 0.f;
    for (int k = 0; k < 128; ++k) s += We4[r * 128 + k] * Wt[k * 2 + c];
    sm[SM_T4 + r * 2 + c] = s;
  }
  __syncthreads();
  {
    int r = tid >> 1, c = tid & 1; float s = 0.f;
    for (int k = 0; k < 128; ++k) s += We3[r * 128 + k] * sm[SM_T4 + k * 2 + c];
    sm[SM_T3 + r * 2 + c] = s;
  }
  __syncthreads();
  {
    int r = tid >> 1, c = tid & 1; float s = 0.f;
    for (int k = 0; k < 128; ++k) s += We2[r * 128 + k] * sm[SM_T3 + k * 2 + c];
    sm[SM_T2 + r * 2 + c] = s;
  }
  __syncthreads();
  {
    int r = tid >> 1, c = tid & 1; float s = 0.f;
    for (int k = 0; k < 128; ++k) s += We1[r * 128 + k] * sm[SM_T2 + k * 2 + c];
    sm[SM_ME + r * 2 + c] = s;
  }
  // W2c = W2@Wc  (256x16)
  for (int o = tid; o < 4096; o += 256) {
    int r = o >> 4, c = o & 15; float s = 0.f;
    for (int k = 0; k < 128; ++k) s += W2[r * 128 + k] * Wc[k * 16 + c];
    sm[SM_W2C + o] = s;
  }
  if (tid < 16) {
    float s = 0.f;
    for (int k = 0; k < 128; ++k) s += b2[k] * Wc[k * 16 + tid];
    sm[SM_CLSC + tid] = s + bc[tid];
  }
  __syncthreads();
  if (tid < 2) {
    float s = 0.f;
    for (int k = 0; k < 128; ++k) s += be1[k] * sm[SM_T2 + k * 2 + tid];
    sm[SM_C1 + tid] = s;
    s = 0.f;
    for (int k = 0; k < 128; ++k) s += be2[k] * sm[SM_T3 + k * 2 + tid];
    sm[SM_C2 + tid] = s;
    s = 0.f;
    for (int k = 0; k < 128; ++k) s += be3[k] * sm[SM_T4 + k * 2 + tid];
    sm[SM_C3 + tid] = s;
    s = 0.f;
    for (int k = 0; k < 128; ++k) s += be4[k] * Wt[k * 2 + tid];
    sm[SM_FC + tid] = s + bt[tid];
  }
}

// ax = A'x (wave per node, lane holds 2 feats) + fused g1 = ax@Me + c1
__global__ __launch_bounds__(256) void k_agg128(
    const float* __restrict__ x, const int* __restrict__ rowptr,
    const int* __restrict__ csr_src, const float* __restrict__ csr_w,
    const float* __restrict__ dis, const float* __restrict__ sm,
    float* __restrict__ ax, float* __restrict__ ga, int N) {
  int node = blockIdx.x * 4 + (threadIdx.x >> 6);
  if (node >= N) return;
  int lane = threadIdx.x & 63;
  const float2* x2 = (const float2*)x;
  float d = dis[node];
  float2 v = x2[(size_t)node * 64 + lane];
  float a0 = d * d * v.x, a1 = d * d * v.y;
  int e = rowptr[node], end = rowptr[node + 1];
  for (; e + 1 < end; e += 2) {
    int s0 = csr_src[e], s1 = csr_src[e + 1];
    float w0 = csr_w[e], w1 = csr_w[e + 1];
    float2 u0 = x2[(size_t)s0 * 64 + lane];
    float2 u1 = x2[(size_t)s1 * 64 + lane];
    a0 = fmaf(w0, u0.x, a0); a1 = fmaf(w0, u0.y, a1);
    a0 = fmaf(w1, u1.x, a0); a1 = fmaf(w1, u1.y, a1);
  }
  if (e < end) {
    int s0 = csr_src[e]; float w0 = csr_w[e];
    float2 u0 = x2[(size_t)s0 * 64 + lane];
    a0 = fmaf(w0, u0.x, a0); a1 = fmaf(w0, u0.y, a1);
  }
  ((float2*)ax)[(size_t)node * 64 + lane] = make_float2(a0, a1);
  // g1 epilogue: lane covers feats 2l, 2l+1
  float4 me = *(const float4*)&sm[SM_ME + lane * 4];
  float p0 = a0 * me.x + a1 * me.z;
  float p1 = a0 * me.y + a1 * me.w;
  #pragma unroll
  for (int m = 32; m; m >>= 1) { p0 += __shfl_xor(p0, m); p1 += __shfl_xor(p1, m); }
  if (lane == 0)
    ((float2*)ga)[node] = make_float2(p0 + sm[SM_C1 + 0], p1 + sm[SM_C1 + 1]);
}

// y16 = relu(ax @ W1 + b1) @ W2c, fused.  BM=128, per-block loop over two
// 128-col halves; per-thread p[8][16] partial of y16, shfl-reduced over tx.
__global__ __launch_bounds__(256) void k_gemm_fused(
    const float* __restrict__ A, const float* __restrict__ W1,
    const float* __restrict__ b1, const float* __restrict__ sm,
    float* __restrict__ Y, int N) {
  __shared__ float As[32][132];  // transposed [k][row], padded
  __shared__ float Bs[32][132];
  int tid = threadIdx.x;
  int tx = tid & 15, ty = tid >> 4;
  int m0 = blockIdx.x * 128;
  float p[8][16];
  #pragma unroll
  for (int i = 0; i < 8; ++i)
    #pragma unroll
    for (int c = 0; c < 16; ++c) p[i][c] = 0.f;

  for (int n0 = 0; n0 < 256; n0 += 128) {
    float acc[8][8];
    #pragma unroll
    for (int i = 0; i < 8; ++i)
      #pragma unroll
      for (int j = 0; j < 8; ++j) acc[i][j] = 0.f;

    for (int k0 = 0; k0 < 128; k0 += 32) {
      __syncthreads();
      #pragma unroll
      for (int it = 0; it < 4; ++it) {
        int idx = it * 256 + tid;
        int row = idx >> 3, k4 = (idx & 7) << 2;
        int gr = m0 + row; gr = gr < N ? gr : N - 1;
        float4 va = *(const float4*)&A[(size_t)gr * 128 + k0 + k4];
        As[k4 + 0][row] = va.x; As[k4 + 1][row] = va.y;
        As[k4 + 2][row] = va.z; As[k4 + 3][row] = va.w;
        int kb = idx >> 5, c4 = (idx & 31) << 2;
        float4 vb = *(const float4*)&W1[(size_t)(k0 + kb) * 256 + n0 + c4];
        *(float4*)&Bs[kb][c4] = vb;
      }
      __syncthreads();
      #pragma unroll
      for (int k = 0; k < 32; ++k) {
        float4 a0 = *(const float4*)&As[k][ty * 8];
        float4 a1 = *(const float4*)&As[k][ty * 8 + 4];
        float4 b0 = *(const float4*)&Bs[k][tx * 8];
        float4 b1v = *(const float4*)&Bs[k][tx * 8 + 4];
        float a[8] = {a0.x, a0.y, a0.z, a0.w, a1.x, a1.y, a1.z, a1.w};
        float b[8] = {b0.x, b0.y, b0.z, b0.w, b1v.x, b1v.y, b1v.z, b1v.w};
        #pragma unroll
        for (int i = 0; i < 8; ++i)
          #pragma unroll
          for (int j = 0; j < 8; ++j) acc[i][j] = fmaf(a[i], b[j], acc[i][j]);
      }
    }
    // fold: p[i][c] += relu(acc[i][j] + b1[n0+tx*8+j]) * W2c[n0+tx*8+j][c]
    float4 bb0 = *(const float4*)&b1[n0 + tx * 8];
    float4 bb1 = *(const float4*)&b1[n0 + tx * 8 + 4];
    float bb[8] = {bb0.x, bb0.y, bb0.z, bb0.w, bb1.x, bb1.y, bb1.z, bb1.w};
    #pragma unroll
    for (int j = 0; j < 8; ++j) {
      const float* wr = &sm[SM_W2C + (size_t)(n0 + tx * 8 + j) * 16];
      float4 w0 = *(const float4*)&wr[0];
      float4 w1 = *(const float4*)&wr[4];
      float4 w2 = *(const float4*)&wr[8];
      float4 w3 = *(const float4*)&wr[12];
      float wj[16] = {w0.x, w0.y, w0.z, w0.w, w1.x, w1.y, w1.z, w1.w,
                      w2.x, w2.y, w2.z, w2.w, w3.x, w3.y, w3.z, w3.w};
      #pragma unroll
      for (int i = 0; i < 8; ++i) {
        float o = acc[i][j] + bb[j];
        o = o > 0.f ? o : 0.f;
        #pragma unroll
        for (int c = 0; c < 16; ++c) p[i][c] = fmaf(o, wj[c], p[i][c]);
      }
    }
  }
  // reduce p over the 16 tx lanes (lane bits 0..3 within the wave)
  #pragma unroll
  for (int i = 0; i < 8; ++i)
    #pragma unroll
    for (int c = 0; c < 16; ++c) {
      float v = p[i][c];
      v += __shfl_xor(v, 1);
      v += __shfl_xor(v, 2);
      v += __shfl_xor(v, 4);
      v += __shfl_xor(v, 8);
      p[i][c] = v;
    }
  if (tx == 0) {
    #pragma unroll
    for (int i = 0; i < 8; ++i) {
      int gr = m0 + ty * 8 + i;
      if (gr < N) {
        *(float4*)&Y[(size_t)gr * 16 + 0]  = make_float4(p[i][0], p[i][1], p[i][2], p[i][3]);
        *(float4*)&Y[(size_t)gr * 16 + 4]  = make_float4(p[i][4], p[i][5], p[i][6], p[i][7]);
        *(float4*)&Y[(size_t)gr * 16 + 8]  = make_float4(p[i][8], p[i][9], p[i][10], p[i][11]);
        *(float4*)&Y[(size_t)gr * 16 + 12] = make_float4(p[i][12], p[i][13], p[i][14], p[i][15]);
      }
    }
  }
}

// cls = A'(y16) + cls_const  (16 lanes per node) -> d_out
__global__ __launch_bounds__(256) void k_agg16(
    const float* __restrict__ Y, const int* __restrict__ rowptr,
    const int* __restrict__ csr_src, const float* __restrict__ csr_w,
    const float* __restrict__ dis, const float* __restrict__ sm,
    float* __restrict__ out, int N) {
  int node = blockIdx.x * 16 + (threadIdx.x >> 4);
  if (node >= N) return;
  int sl = threadIdx.x & 15;
  float d = dis[node];
  float acc = d * d * Y[(size_t)node * 16 + sl];
  int e = rowptr[node], end = rowptr[node + 1];
  for (; e < end; ++e) {
    int s = csr_src[e]; float w = csr_w[e];
    acc = fmaf(w, Y[(size_t)s * 16 + sl], acc);
  }
  out[(size_t)node * 16 + sl] = acc + sm[SM_CLSC + sl];
}

// g_out = A'(g_in) + cadd  (2 feats, thread per node); FINAL adds sigmoid
template <int FINAL>
__global__ __launch_bounds__(256) void k_agg2(
    const float* __restrict__ gin, const int* __restrict__ rowptr,
    const int* __restrict__ csr_src, const float* __restrict__ csr_w,
    const float* __restrict__ dis, const float* __restrict__ cadd,
    float* __restrict__ gout, int N) {
  int i = blockIdx.x * 256 + threadIdx.x;
  if (i >= N) return;
  const float2* g2 = (const float2*)gin;
  float d = dis[i];
  float2 v = g2[i];
  float a0 = d * d * v.x, a1 = d * d * v.y;
  int e = rowptr[i], end = rowptr[i + 1];
  for (; e < end; ++e) {
    int s = csr_src[e]; float w = csr_w[e];
    float2 u = g2[s];
    a0 = fmaf(w, u.x, a0); a1 = fmaf(w, u.y, a1);
  }
  a0 += cadd[0]; a1 += cadd[1];
  if (FINAL) {
    a0 = 1.f / (1.f + expf(-a0));
    a1 = 1.f / (1.f + expf(-a1));
  }
  ((float2*)gout)[i] = make_float2(a0, a1);
}

extern "C" void kernel_launch(void* const* d_in, const int* in_sizes, int n_in,
                              void* d_out, int out_size, void* d_ws, size_t ws_size,
                              hipStream_t stream) {
  const float* x = (const float*)d_in[0];
  const int* ei = (const int*)d_in[1];   // int32! (JAX x64 disabled)
  const float* W1 = (const float*)d_in[2];
  const float* b1 = (const float*)d_in[3];
  const float* W2 = (const float*)d_in[4];
  const float* b2 = (const float*)d_in[5];
  const float* Wc = (const float*)d_in[6];
  const float* bc = (const float*)d_in[7];
  const float* We1 = (const float*)d_in[8];
  const float* be1 = (const float*)d_in[9];
  const float* We2 = (const float*)d_in[10];
  const float* be2 = (const float*)d_in[11];
  const float* We3 = (const float*)d_in[12];
  const float* be3 = (const float*)d_in[13];
  const float* We4 = (const float*)d_in[14];
  const float* be4 = (const float*)d_in[15];
  const float* Wt = (const float*)d_in[16];
  const float* bt = (const float*)d_in[17];
  float* out = (float*)d_out;

  const int N = in_sizes[0] / 128;
  const int E = in_sizes[1] / 2;

  char* ws = (char*)d_ws;
  size_t off = 0;
  auto alloc = [&](size_t bytes) {
    size_t o = off;
    off = (off + bytes + 255) & ~(size_t)255;
    return o;
  };
  int* deg = (int*)(ws + alloc((size_t)N * 4));
  int* cnt = (int*)(ws + alloc((size_t)N * 4));
  int* rowptr = (int*)(ws + alloc(((size_t)N + 1) * 4));
  float* dis = (float*)(ws + alloc((size_t)N * 4));
  int* csr_src = (int*)(ws + alloc((size_t)E * 4));
  float* csr_w = (float*)(ws + alloc((size_t)E * 4));
  float* ax = (float*)(ws + alloc((size_t)N * 128 * 4));
  float* y16 = (float*)(ws + alloc((size_t)N * 16 * 4));
  float* ga = (float*)(ws + alloc((size_t)N * 2 * 4));
  float* gb = (float*)(ws + alloc((size_t)N * 2 * 4));
  float* sm = (float*)(ws + alloc((size_t)SM_TOTAL * 4));
  // total ≈ 68 MB of ws

  hipMemsetAsync(deg, 0, (size_t)N * 4, stream);
  hipMemsetAsync(cnt, 0, (size_t)N * 4, stream);

  k_precompute<<<1, 256, 0, stream>>>(W2, b2, Wc, bc, We1, be1, We2, be2, We3,
                                      be3, We4, be4, Wt, bt, sm);
  k_deg<<<(E + 255) / 256, 256, 0, stream>>>(ei, deg, E, N);
  k_dis<<<(N + 255) / 256, 256, 0, stream>>>(deg, dis, N);
  k_scan<<<1, 1024, 0, stream>>>(deg, rowptr, N);
  k_scatter<<<(E + 255) / 256, 256, 0, stream>>>(ei, rowptr, cnt, dis, csr_src,
                                                 csr_w, E, N);
  k_agg128<<<(N + 3) / 4, 256, 0, stream>>>(x, rowptr, csr_src, csr_w, dis, sm,
                                            ax, ga, N);
  k_gemm_fused<<<(N + 127) / 128, 256, 0, stream>>>(ax, W1, b1, sm, y16, N);
  k_agg16<<<(N + 15) / 16, 256, 0, stream>>>(y16, rowptr, csr_src, csr_w, dis,
                                             sm, out, N);
  k_agg2<0><<<(N + 255) / 256, 256, 0, stream>>>(ga, rowptr, csr_src, csr_w,
                                                 dis, sm + SM_C2, gb, N);
  k_agg2<0><<<(N + 255) / 256, 256, 0, stream>>>(gb, rowptr, csr_src, csr_w,
                                                 dis, sm + SM_C3, ga, N);
  k_agg2<1><<<(N + 255) / 256, 256, 0, stream>>>(
      ga, rowptr, csr_src, csr_w, dis, sm + SM_FC, out + (size_t)N * 16, N);
}